// Round 2
// baseline (630.568 us; speedup 1.0000x reference)
//
#include <hip/hip_runtime.h>
#include <hip/hip_bf16.h>

#define D_MODEL 256
#define N_ROWS  262144      // B * FEATS_PER_IMAGE
#define N_Q     1024        // B * Q_PER_IMAGE

typedef __attribute__((ext_vector_type(8))) short short8;
typedef __attribute__((ext_vector_type(16))) float floatx16;

static __device__ __forceinline__ short f2bf(float x) {
    union { __hip_bfloat16 h; short s; } u;
    u.h = __float2bfloat16(x);
    return u.s;
}

// ---------------------------------------------------------------------------
// Kernel 1: 4-layer MLP on queries, fp32 compute, bf16 output to workspace.
// (unchanged from verified baseline)
// ---------------------------------------------------------------------------
__global__ __launch_bounds__(256) void mlp_kernel(
    const float* __restrict__ q,
    const float* __restrict__ W1, const float* __restrict__ b1,
    const float* __restrict__ W2, const float* __restrict__ b2,
    const float* __restrict__ W3, const float* __restrict__ b3,
    const float* __restrict__ W4, const float* __restrict__ b4,
    __hip_bfloat16* __restrict__ xout)
{
    __shared__ float cur[4][D_MODEL];
    const int j = threadIdx.x;
    const int row0 = blockIdx.x * 4;

    #pragma unroll
    for (int i = 0; i < 4; i++)
        cur[i][j] = q[(long)(row0 + i) * D_MODEL + j];
    __syncthreads();

    const float* Ws[4] = { W1, W2, W3, W4 };
    const float* bs[4] = { b1, b2, b3, b4 };

    for (int l = 0; l < 4; l++) {
        const float4* wrow = (const float4*)(Ws[l] + (long)j * D_MODEL);
        float acc0 = bs[l][j];
        float acc1 = acc0, acc2 = acc0, acc3 = acc0;
        #pragma unroll 8
        for (int k = 0; k < D_MODEL / 4; k++) {
            float4 w  = wrow[k];
            float4 c0 = ((const float4*)cur[0])[k];
            float4 c1 = ((const float4*)cur[1])[k];
            float4 c2 = ((const float4*)cur[2])[k];
            float4 c3 = ((const float4*)cur[3])[k];
            acc0 += w.x*c0.x + w.y*c0.y + w.z*c0.z + w.w*c0.w;
            acc1 += w.x*c1.x + w.y*c1.y + w.z*c1.z + w.w*c1.w;
            acc2 += w.x*c2.x + w.y*c2.y + w.z*c2.z + w.w*c2.w;
            acc3 += w.x*c3.x + w.y*c3.y + w.z*c3.z + w.w*c3.w;
        }
        __syncthreads();
        if (l < 3) {
            cur[0][j] = fmaxf(acc0, 0.f);
            cur[1][j] = fmaxf(acc1, 0.f);
            cur[2][j] = fmaxf(acc2, 0.f);
            cur[3][j] = fmaxf(acc3, 0.f);
            __syncthreads();
        } else {
            xout[(long)(row0 + 0) * D_MODEL + j] = __float2bfloat16(acc0);
            xout[(long)(row0 + 1) * D_MODEL + j] = __float2bfloat16(acc1);
            xout[(long)(row0 + 2) * D_MODEL + j] = __float2bfloat16(acc2);
            xout[(long)(row0 + 3) * D_MODEL + j] = __float2bfloat16(acc3);
        }
    }
}

// ---------------------------------------------------------------------------
// Kernel 2: per-batch NT GEMM, fully streaming — NO LDS, NO barriers.
// Block = 4 waves = 64 rows x 256 cols; wave tile 32x128 = 1x4 mfma_32x32x16.
// A-fragments load straight from global fp32 (8 consecutive floats/lane,
// per-row 64 B chunks = full sectors), cvt to bf16 in-register.  The two
// waves sharing a 32-row group (wc=0/1) are co-resident on the CU -> L1/L2
// serves the second read; HBM sees F exactly once.  B (X, 512 KB bf16) is
// L2-resident, loaded per fragment as before.  0 LDS + VGPR<=128 ->
// 16 waves/CU, every wave independently keeps loads in flight: the memory
// pipe never drains on a barrier.
// ---------------------------------------------------------------------------
__global__ __launch_bounds__(256, 4) void logits_kernel(
    const float* __restrict__ F,            // [262144, 256] fp32
    const __hip_bfloat16* __restrict__ X,   // [1024, 256] bf16
    float* __restrict__ out)                // [262144, 256] fp32
{
    const int t    = threadIdx.x;
    const int wave = t >> 6;
    const int lane = t & 63;
    const int m    = lane & 31;     // row-in-32 (A) / col-in-32 (B)
    const int kg   = lane >> 5;     // k-group: k offset = kg*8
    const int wr   = wave >> 1;     // row-group within block (0..1)
    const int wc   = wave & 1;      // col-group within block (0..1)

    const long row0  = (long)blockIdx.x * 64;
    const int  batch = (int)(row0 >> 16);       // 65536 rows per batch

    const float* aptr = F + (row0 + wr * 32 + m) * D_MODEL + kg * 8;
    const __hip_bfloat16* bptr =
        X + ((long)(batch << 8) + (wc << 7) + m) * D_MODEL + kg * 8;

    floatx16 acc0 = {0.f}, acc1 = {0.f}, acc2 = {0.f}, acc3 = {0.f};

    #pragma unroll 4
    for (int ks = 0; ks < 16; ks++) {
        const int k0 = ks * 16;     // this lane covers k0+kg*8 .. +8

        float4 alo = *(const float4*)(aptr + k0);       // global fp32, HBM stream
        float4 ahi = *(const float4*)(aptr + k0 + 4);
        union { short8 v; short s[8]; } af;
        af.s[0] = f2bf(alo.x); af.s[1] = f2bf(alo.y);
        af.s[2] = f2bf(alo.z); af.s[3] = f2bf(alo.w);
        af.s[4] = f2bf(ahi.x); af.s[5] = f2bf(ahi.y);
        af.s[6] = f2bf(ahi.z); af.s[7] = f2bf(ahi.w);

        short8 b0 = *(const short8*)(bptr + k0);                  // L2-hot
        short8 b1 = *(const short8*)(bptr + 32 * D_MODEL + k0);
        short8 b2 = *(const short8*)(bptr + 64 * D_MODEL + k0);
        short8 b3 = *(const short8*)(bptr + 96 * D_MODEL + k0);

        acc0 = __builtin_amdgcn_mfma_f32_32x32x16_bf16(af.v, b0, acc0, 0, 0, 0);
        acc1 = __builtin_amdgcn_mfma_f32_32x32x16_bf16(af.v, b1, acc1, 0, 0, 0);
        acc2 = __builtin_amdgcn_mfma_f32_32x32x16_bf16(af.v, b2, acc2, 0, 0, 0);
        acc3 = __builtin_amdgcn_mfma_f32_32x32x16_bf16(af.v, b3, acc3, 0, 0, 0);
    }

    // C/D layout (verified m74/m101): col = lane&31, row = (reg&3) + 8*(reg>>2) + 4*(lane>>5)
    // Nontemporal stores: out is never re-read; keep it out of L3 so F stays cached.
    const long rbase   = row0 + wr * 32 + 4 * kg;
    const int  colbase = (wc << 7) + m;
    #pragma unroll
    for (int reg = 0; reg < 16; reg++) {
        const int r = (reg & 3) + 8 * (reg >> 2);
        float* orow = out + (rbase + r) * D_MODEL + colbase;
        __builtin_nontemporal_store(acc0[reg], orow);
        __builtin_nontemporal_store(acc1[reg], orow + 32);
        __builtin_nontemporal_store(acc2[reg], orow + 64);
        __builtin_nontemporal_store(acc3[reg], orow + 96);
    }
}

extern "C" void kernel_launch(void* const* d_in, const int* in_sizes, int n_in,
                              void* d_out, int out_size, void* d_ws, size_t ws_size,
                              hipStream_t stream) {
    const float* queries = (const float*)d_in[0];
    const float* feats   = (const float*)d_in[1];
    // d_in[2] feature_indices, d_in[3] query_batch_offsets: not needed for values
    const float* W1 = (const float*)d_in[4];
    const float* b1 = (const float*)d_in[5];
    const float* W2 = (const float*)d_in[6];
    const float* b2 = (const float*)d_in[7];
    const float* W3 = (const float*)d_in[8];
    const float* b3 = (const float*)d_in[9];
    const float* W4 = (const float*)d_in[10];
    const float* b4 = (const float*)d_in[11];

    __hip_bfloat16* x_bf16 = (__hip_bfloat16*)d_ws;   // [1024, 256] bf16 = 512 KB

    mlp_kernel<<<N_Q / 4, 256, 0, stream>>>(queries, W1, b1, W2, b2, W3, b3, W4, b4, x_bf16);
    logits_kernel<<<N_ROWS / 64, 256, 0, stream>>>(feats, x_bf16, (float*)d_out);
}

// Round 3
// 612.792 us; speedup vs baseline: 1.0290x; 1.0290x over previous
//
#include <hip/hip_runtime.h>
#include <hip/hip_bf16.h>

#define D_MODEL 256
#define N_ROWS  262144      // B * FEATS_PER_IMAGE
#define N_Q     1024        // B * Q_PER_IMAGE

typedef __attribute__((ext_vector_type(8))) short short8;
typedef __attribute__((ext_vector_type(16))) float floatx16;

static __device__ __forceinline__ short f2bf(float x) {
    union { __hip_bfloat16 h; short s; } u;
    u.h = __float2bfloat16(x);
    return u.s;
}

// ---------------------------------------------------------------------------
// Kernel 1: 4-layer MLP on queries, fp32 compute, bf16 output to workspace.
// (unchanged from verified baseline)
// ---------------------------------------------------------------------------
__global__ __launch_bounds__(256) void mlp_kernel(
    const float* __restrict__ q,
    const float* __restrict__ W1, const float* __restrict__ b1,
    const float* __restrict__ W2, const float* __restrict__ b2,
    const float* __restrict__ W3, const float* __restrict__ b3,
    const float* __restrict__ W4, const float* __restrict__ b4,
    __hip_bfloat16* __restrict__ xout)
{
    __shared__ float cur[4][D_MODEL];
    const int j = threadIdx.x;
    const int row0 = blockIdx.x * 4;

    #pragma unroll
    for (int i = 0; i < 4; i++)
        cur[i][j] = q[(long)(row0 + i) * D_MODEL + j];
    __syncthreads();

    const float* Ws[4] = { W1, W2, W3, W4 };
    const float* bs[4] = { b1, b2, b3, b4 };

    for (int l = 0; l < 4; l++) {
        const float4* wrow = (const float4*)(Ws[l] + (long)j * D_MODEL);
        float acc0 = bs[l][j];
        float acc1 = acc0, acc2 = acc0, acc3 = acc0;
        #pragma unroll 8
        for (int k = 0; k < D_MODEL / 4; k++) {
            float4 w  = wrow[k];
            float4 c0 = ((const float4*)cur[0])[k];
            float4 c1 = ((const float4*)cur[1])[k];
            float4 c2 = ((const float4*)cur[2])[k];
            float4 c3 = ((const float4*)cur[3])[k];
            acc0 += w.x*c0.x + w.y*c0.y + w.z*c0.z + w.w*c0.w;
            acc1 += w.x*c1.x + w.y*c1.y + w.z*c1.z + w.w*c1.w;
            acc2 += w.x*c2.x + w.y*c2.y + w.z*c2.z + w.w*c2.w;
            acc3 += w.x*c3.x + w.y*c3.y + w.z*c3.z + w.w*c3.w;
        }
        __syncthreads();
        if (l < 3) {
            cur[0][j] = fmaxf(acc0, 0.f);
            cur[1][j] = fmaxf(acc1, 0.f);
            cur[2][j] = fmaxf(acc2, 0.f);
            cur[3][j] = fmaxf(acc3, 0.f);
            __syncthreads();
        } else {
            xout[(long)(row0 + 0) * D_MODEL + j] = __float2bfloat16(acc0);
            xout[(long)(row0 + 1) * D_MODEL + j] = __float2bfloat16(acc1);
            xout[(long)(row0 + 2) * D_MODEL + j] = __float2bfloat16(acc2);
            xout[(long)(row0 + 3) * D_MODEL + j] = __float2bfloat16(acc3);
        }
    }
}

// ---------------------------------------------------------------------------
// Kernel 2: per-batch NT GEMM, pipelined multi-tile blocks (T14 split).
// Block = 4 waves; per tile: 32 rows x 256 cols; wave tile 32x64 = 1x2
// mfma_32x32x16.  Each block owns 8 consecutive 32-row tiles (256 rows,
// never crosses a batch boundary: 65536 % 256 == 0).
//
// Schedule per iteration (single 16.9 KB LDS buffer, barrier-protected):
//   cvt+ds_write(pend)  -> barrier          (tile t becomes readable)
//   issue 8 coalesced float4 loads(tile t+1) -> pend   [HBM latency starts]
//   compute tile t (16 k-steps, A from LDS, B from L1/L2-hot X)
//   nt-store tile t                          [latency of pend hides here]
//   barrier                                  (all waves done reading LDS)
//
// Staging loads keep the old kernel's proven wave-contiguous pattern
// (1 KB/instruction, 16 lines) — the round-2 regression showed per-lane
// strided gathers (64 lines/instruction) collapse achievable BW.
// XCD-aware swizzle (1024 blocks % 8 == 0, bijective): each XCD's blocks
// share one batch's X-slice (128 KB, L2-resident).
// ---------------------------------------------------------------------------
#define APAD 264
#define BM   32          // rows per tile
#define TILES_PER_BLOCK 8

__global__ __launch_bounds__(256) void logits_kernel(
    const float* __restrict__ F,            // [262144, 256] fp32
    const __hip_bfloat16* __restrict__ X,   // [1024, 256] bf16
    float* __restrict__ out)                // [262144, 256] fp32
{
    __shared__ __hip_bfloat16 As[BM * APAD];   // 16896 B

    const int t    = threadIdx.x;
    const int wave = t >> 6;
    const int lane = t & 63;
    const int m    = lane & 31;     // row-in-32 (A) / col-in-32 (B)
    const int kg   = lane >> 5;     // k-group: k offset = kg*8

    // XCD swizzle: dispatch round-robins blockIdx%8 across XCDs; give each
    // XCD a contiguous chunk of row-space (one batch spans 2 XCDs).
    int b = blockIdx.x;
    b = (b & 7) * (1024 / 8) + (b >> 3);

    const long row00 = (long)b * (BM * TILES_PER_BLOCK);   // 256 rows/block
    const int  batch = (int)(row00 >> 16);                 // 65536 rows/batch

    const __hip_bfloat16* bb =
        X + ((long)(batch << 8) + (wave << 6) + m) * D_MODEL + kg * 8;

    // ---- prologue: load tile 0 into pending regs (coalesced) ----
    float4 pend[8];
    {
        const float4* Fb = (const float4*)(F + row00 * D_MODEL);
        #pragma unroll
        for (int i = 0; i < 8; i++)
            pend[i] = Fb[i * 256 + t];
    }

    for (int tt = 0; tt < TILES_PER_BLOCK; tt++) {
        // ---- write pending tile to LDS (cvt fp32 -> bf16) ----
        #pragma unroll
        for (int i = 0; i < 8; i++) {
            const int flat = i * 256 + t;        // float4 index in 32x256 tile
            const int row  = flat >> 6;          // 64 float4 per row
            const int c4   = (flat & 63) << 2;   // float col
            union { ushort4 u; short s[4]; } w;
            w.s[0] = f2bf(pend[i].x); w.s[1] = f2bf(pend[i].y);
            w.s[2] = f2bf(pend[i].z); w.s[3] = f2bf(pend[i].w);
            *(ushort4*)(&As[row * APAD + c4]) = w.u;
        }
        __syncthreads();

        // ---- issue next tile's loads early (hide HBM latency under compute) ----
        if (tt < TILES_PER_BLOCK - 1) {
            const float4* Fb =
                (const float4*)(F + (row00 + (long)(tt + 1) * BM) * D_MODEL);
            #pragma unroll
            for (int i = 0; i < 8; i++)
                pend[i] = Fb[i * 256 + t];
        }

        // ---- compute tile tt ----
        const __hip_bfloat16* a0 = &As[m * APAD + kg * 8];
        floatx16 acc0 = {0.f}, acc1 = {0.f};

        #pragma unroll 4
        for (int ks = 0; ks < 16; ks++) {
            const int k0 = ks * 16;
            short8 af  = *(const short8*)(a0 + k0);               // ds_read_b128
            short8 bf0 = *(const short8*)(bb + k0);               // L1/L2-hot
            short8 bf1 = *(const short8*)(bb + 32 * D_MODEL + k0);
            acc0 = __builtin_amdgcn_mfma_f32_32x32x16_bf16(af, bf0, acc0, 0, 0, 0);
            acc1 = __builtin_amdgcn_mfma_f32_32x32x16_bf16(af, bf1, acc1, 0, 0, 0);
        }

        // ---- store tile tt ----
        // C/D layout (m74/m101): col = lane&31, row = (reg&3)+8*(reg>>2)+4*(lane>>5)
        const long rbase   = row00 + (long)tt * BM + 4 * kg;
        const int  colbase = (wave << 6) + m;
        #pragma unroll
        for (int reg = 0; reg < 16; reg++) {
            const int r = (reg & 3) + 8 * (reg >> 2);
            float* orow = out + (rbase + r) * D_MODEL + colbase;
            __builtin_nontemporal_store(acc0[reg], orow);
            __builtin_nontemporal_store(acc1[reg], orow + 32);
        }

        __syncthreads();   // all waves done reading As before next ds_write
    }
}

extern "C" void kernel_launch(void* const* d_in, const int* in_sizes, int n_in,
                              void* d_out, int out_size, void* d_ws, size_t ws_size,
                              hipStream_t stream) {
    const float* queries = (const float*)d_in[0];
    const float* feats   = (const float*)d_in[1];
    // d_in[2] feature_indices, d_in[3] query_batch_offsets: not needed for values
    const float* W1 = (const float*)d_in[4];
    const float* b1 = (const float*)d_in[5];
    const float* W2 = (const float*)d_in[6];
    const float* b2 = (const float*)d_in[7];
    const float* W3 = (const float*)d_in[8];
    const float* b3 = (const float*)d_in[9];
    const float* W4 = (const float*)d_in[10];
    const float* b4 = (const float*)d_in[11];

    __hip_bfloat16* x_bf16 = (__hip_bfloat16*)d_ws;   // [1024, 256] bf16 = 512 KB

    mlp_kernel<<<N_Q / 4, 256, 0, stream>>>(queries, W1, b1, W2, b2, W3, b3, W4, b4, x_bf16);
    logits_kernel<<<N_ROWS / (BM * TILES_PER_BLOCK), 256, 0, stream>>>(
        feats, x_bf16, (float*)d_out);
}